// Round 1
// baseline (210.088 us; speedup 1.0000x reference)
//
#include <hip/hip_runtime.h>
#include <hip/hip_bf16.h>

#define NPTS 524288
#define DIM 256
#define KC 64

typedef __attribute__((ext_vector_type(8))) short bf16x8;
typedef __attribute__((ext_vector_type(4))) float f32x4;

static __device__ __forceinline__ ushort f32_to_bf16_rne(float f) {
  unsigned int b = __builtin_bit_cast(unsigned int, f);
  b += 0x7FFFu + ((b >> 16) & 1u);   // round-to-nearest-even (inputs are finite)
  return (ushort)(b >> 16);
}

// Kernel 0: clusters fp32 (64x256) -> bf16 into ws, plus c2[k] = sum_d c[k][d]^2 (fp32).
__global__ void prep_clusters(const float* __restrict__ C,
                              ushort* __restrict__ cb,
                              float* __restrict__ c2) {
  const int lane = threadIdx.x & 63;
  const int row = blockIdx.x * 4 + (threadIdx.x >> 6);  // one wave per cluster row
  const float* src = C + row * DIM;
  ushort* dst = cb + row * DIM;
  float s = 0.f;
#pragma unroll
  for (int i = 0; i < 4; ++i) {
    float v = src[lane + 64 * i];
    s = fmaf(v, v, s);
    dst[lane + 64 * i] = f32_to_bf16_rne(v);
  }
  s += __shfl_xor(s, 1);
  s += __shfl_xor(s, 2);
  s += __shfl_xor(s, 4);
  s += __shfl_xor(s, 8);
  s += __shfl_xor(s, 16);
  s += __shfl_xor(s, 32);
  if (lane == 0) c2[row] = s;
}

// Kernel 1: per wave, a 16-row x 64-col tile of q = normalize(1/(1+||x-c||^2)).
__global__ __launch_bounds__(256, 4)
void cluster_q(const float* __restrict__ A,
               const ushort* __restrict__ Bb,
               const float* __restrict__ c2,
               float* __restrict__ out) {
  const int tid = threadIdx.x;
  const int lane = tid & 63;
  const int wid = tid >> 6;
  const int l15 = lane & 15;   // A-row within tile / C-col within col-tile
  const int g = lane >> 4;     // K-chunk selector (A/B), row-group (C/D)

  const long rowbase = (long)blockIdx.x * 64 + wid * 16;
  const float* Ab = A + rowbase * DIM + (long)l15 * DIM + g * 8;
  const bf16x8* Bv = (const bf16x8*)Bb;

  f32x4 acc[4];
#pragma unroll
  for (int t = 0; t < 4; ++t) acc[t] = (f32x4){0.f, 0.f, 0.f, 0.f};

  float x2l = 0.f;
#pragma unroll
  for (int s = 0; s < 8; ++s) {
    // A fragment: row l15, k = s*32 + g*8 .. +8 (fp32, convert in-register)
    const float4* p = (const float4*)(Ab + s * 32);
    float4 u0 = p[0];
    float4 u1 = p[1];
    float v[8] = {u0.x, u0.y, u0.z, u0.w, u1.x, u1.y, u1.z, u1.w};
    bf16x8 a;
#pragma unroll
    for (int j = 0; j < 8; ++j) {
      x2l = fmaf(v[j], v[j], x2l);
      a[j] = (short)f32_to_bf16_rne(v[j]);
    }
#pragma unroll
    for (int t = 0; t < 4; ++t) {
      // B fragment: cluster row (l15+16t), k = s*32 + g*8 .. +8 (contiguous bf16x8)
      bf16x8 b = Bv[(l15 + 16 * t) * (DIM / 8) + s * 4 + g];
      acc[t] = __builtin_amdgcn_mfma_f32_16x16x32_bf16(a, b, acc[t], 0, 0, 0);
    }
  }

  // x2 per tile-row: reduce over the 4 K-chunk lane groups (lanes l, l^16, l^32, l^48)
  x2l += __shfl_xor(x2l, 16);
  x2l += __shfl_xor(x2l, 32);
  // now lane i (i<16, and all lanes with l15==i) holds x2 of tile-row i

  float x2r[4];
#pragma unroll
  for (int r = 0; r < 4; ++r) x2r[r] = __shfl(x2l, g * 4 + r);  // x2 of C/D row g*4+r

  float c2v[4];
#pragma unroll
  for (int t = 0; t < 4; ++t) c2v[t] = c2[l15 + 16 * t];

  float q[4][4];
  float rsum[4] = {0.f, 0.f, 0.f, 0.f};
#pragma unroll
  for (int t = 0; t < 4; ++t) {
#pragma unroll
    for (int r = 0; r < 4; ++r) {
      float d2 = x2r[r] + c2v[t] - 2.0f * acc[t][r];
      d2 = fmaxf(d2, 0.f);
      float qq = 1.0f / (1.0f + d2);   // ALPHA=1, exponent (ALPHA+1)/2 = 1
      q[t][r] = qq;
      rsum[r] += qq;
    }
  }
  // row sum across the 16 cols held by this 16-lane group, all 4 col-tiles already local
#pragma unroll
  for (int r = 0; r < 4; ++r) {
    rsum[r] += __shfl_xor(rsum[r], 1);
    rsum[r] += __shfl_xor(rsum[r], 2);
    rsum[r] += __shfl_xor(rsum[r], 4);
    rsum[r] += __shfl_xor(rsum[r], 8);
  }
#pragma unroll
  for (int r = 0; r < 4; ++r) {
    float inv = 1.0f / rsum[r];
    long row = rowbase + g * 4 + r;
#pragma unroll
    for (int t = 0; t < 4; ++t) {
      out[row * KC + l15 + 16 * t] = q[t][r] * inv;
    }
  }
}

extern "C" void kernel_launch(void* const* d_in, const int* in_sizes, int n_in,
                              void* d_out, int out_size, void* d_ws, size_t ws_size,
                              hipStream_t stream) {
  const float* inputs = (const float*)d_in[0];
  const float* clusters = (const float*)d_in[1];
  float* out = (float*)d_out;

  ushort* cb = (ushort*)d_ws;                                  // 64*256 bf16 = 32 KiB
  float* c2 = (float*)((char*)d_ws + KC * DIM * sizeof(ushort));  // 64 floats

  prep_clusters<<<KC / 4, 256, 0, stream>>>(clusters, cb, c2);
  cluster_q<<<NPTS / 64, 256, 0, stream>>>(inputs, cb, c2, out);
}

// Round 2
// 133.920 us; speedup vs baseline: 1.5688x; 1.5688x over previous
//
#include <hip/hip_runtime.h>
#include <hip/hip_bf16.h>

#define NPTS 524288
#define DIM 256
#define KC 64

typedef __attribute__((ext_vector_type(8))) short bf16x8;
typedef __attribute__((ext_vector_type(4))) float f32x4;

typedef __attribute__((address_space(1))) const unsigned int GUI;
typedef __attribute__((address_space(3))) unsigned int LUI;

static __device__ __forceinline__ void gload16(const void* g, void* l) {
  __builtin_amdgcn_global_load_lds((GUI*)g, (LUI*)l, 16, 0, 0);
}

static __device__ __forceinline__ ushort f32_to_bf16_rne(float f) {
  unsigned int b = __builtin_bit_cast(unsigned int, f);
  b += 0x7FFFu + ((b >> 16) & 1u);   // RNE; inputs finite
  return (ushort)(b >> 16);
}

// ws image (32 KiB): slot s holds cluster 4*(s%16)+s/16; 16-B granule m of slot s
// lives at byte s*512 + ((m ^ (s&7))<<4). c2 (natural cluster order) at +32768.
__global__ void prep_clusters(const float* __restrict__ C,
                              char* __restrict__ cb,
                              float* __restrict__ c2) {
  const int w = threadIdx.x >> 6;
  const int lane = threadIdx.x & 63;
  const int k = blockIdx.x * 8 + w * 2 + (lane >> 5);  // cluster
  const int m = lane & 31;                             // 16-B granule (8 elems)
  const float* src = C + k * DIM + m * 8;
  float4 u0 = ((const float4*)src)[0];
  float4 u1 = ((const float4*)src)[1];
  float vv[8] = {u0.x, u0.y, u0.z, u0.w, u1.x, u1.y, u1.z, u1.w};
  float s = 0.f;
  bf16x8 h;
#pragma unroll
  for (int j = 0; j < 8; ++j) {
    s = fmaf(vv[j], vv[j], s);
    h[j] = (short)f32_to_bf16_rne(vv[j]);
  }
  s += __shfl_xor(s, 1);
  s += __shfl_xor(s, 2);
  s += __shfl_xor(s, 4);
  s += __shfl_xor(s, 8);
  s += __shfl_xor(s, 16);
  const int slot = 16 * (k & 3) + (k >> 2);
  const int off = slot * 512 + ((m ^ (slot & 7)) << 4);
  *(bf16x8*)(cb + off) = h;
  if (m == 0) c2[k] = s;
}

// Block: 4 waves, 64 rows (16/wave), all 64 cols. B persistent in LDS[0,32K);
// A wave-private dbuf in LDS[32K,64K): wave w at 32768+w*8192, halves of 4096.
// A chunk = 16 rows x 64 fp32 (256 B/row); within a row, 16-B granule p holds
// logical granule p ^ (row&7)  (source pre-swizzled at stage time).
__global__ __launch_bounds__(256, 2)
void cluster_q(const float* __restrict__ A, const char* __restrict__ cb,
               const float* __restrict__ c2, float* __restrict__ out) {
  __shared__ char lds[65536];
  const int tid = threadIdx.x;
  const int lane = tid & 63;
  const int w = tid >> 6;
  const int l15 = lane & 15;
  const int g = lane >> 4;
  const long brow = (long)blockIdx.x * 64;

  // ---- stage B: 32 KiB linear copy (image already permuted+swizzled)
  {
    const char* src = cb + w * 8192 + lane * 16;
    char* dst = lds + w * 8192;
#pragma unroll
    for (int i = 0; i < 8; ++i)
      gload16(src + i * 1024, dst + i * 1024);
  }

  const char* Arow0 = (const char*)A + (brow + w * 16) * (DIM * 4);

#define STAGE_A(ck, half)                                                    \
  do {                                                                       \
    char* dbase = lds + 32768 + w * 8192 + (half) * 4096;                    \
    _Pragma("unroll") for (int c = 0; c < 4; ++c) {                          \
      int o = c * 1024 + lane * 16;                                          \
      int row = o >> 8;                                                      \
      int kb = ((((o >> 4) & 15) ^ (row & 7)) << 4);                         \
      gload16(Arow0 + row * 1024 + (ck) * 256 + kb, dbase + c * 1024);       \
    }                                                                        \
  } while (0)

  STAGE_A(0, 0);
  STAGE_A(1, 1);
  __syncthreads();  // drains vmcnt(0): B, A0, A1 all resident

  f32x4 acc[4];
#pragma unroll
  for (int t = 0; t < 4; ++t) acc[t] = (f32x4){0.f, 0.f, 0.f, 0.f};
  float x2l = 0.f;

#define KSTEP(ck, s2)                                                        \
  do {                                                                       \
    const char* abuf = lds + 32768 + w * 8192 + ((ck) & 1) * 4096;           \
    int ga = (s2) * 8 + g * 2;                                               \
    int a0 = l15 * 256 + ((ga ^ (l15 & 7)) << 4);                            \
    float4 u0 = *(const float4*)(abuf + a0);                                 \
    float4 u1 = *(const float4*)(abuf + (a0 ^ 16));                          \
    float vv[8] = {u0.x, u0.y, u0.z, u0.w, u1.x, u1.y, u1.z, u1.w};          \
    bf16x8 af;                                                               \
    _Pragma("unroll") for (int j = 0; j < 8; ++j) {                          \
      x2l = fmaf(vv[j], vv[j], x2l);                                         \
      af[j] = (short)f32_to_bf16_rne(vv[j]);                                 \
    }                                                                        \
    int ks = (ck) * 2 + (s2);                                                \
    _Pragma("unroll") for (int t = 0; t < 4; ++t) {                          \
      int slot = l15 + 16 * t;                                               \
      bf16x8 bf = *(const bf16x8*)(lds + slot * 512 +                        \
                                   (((ks * 4 + g) ^ (slot & 7)) << 4));      \
      acc[t] = __builtin_amdgcn_mfma_f32_16x16x32_bf16(af, bf, acc[t], 0, 0, 0); \
    }                                                                        \
  } while (0)

  // counted vmcnt: chunk s needs its 4 gloads done; newest 4 may stay in flight
  asm volatile("s_waitcnt vmcnt(4)" ::: "memory");
  KSTEP(0, 0); KSTEP(0, 1);
  STAGE_A(2, 0);
  asm volatile("s_waitcnt vmcnt(4)" ::: "memory");
  KSTEP(1, 0); KSTEP(1, 1);
  STAGE_A(3, 1);
  asm volatile("s_waitcnt vmcnt(4)" ::: "memory");
  KSTEP(2, 0); KSTEP(2, 1);
  asm volatile("s_waitcnt vmcnt(0)" ::: "memory");
  KSTEP(3, 0); KSTEP(3, 1);

  // ---- epilogue
  x2l += __shfl_xor(x2l, 16);
  x2l += __shfl_xor(x2l, 32);  // full ||x||^2 for row l15, replicated across g
  float x2r[4];
#pragma unroll
  for (int r = 0; r < 4; ++r) x2r[r] = __shfl(x2l, g * 4 + r);

  float4 c2v = *(const float4*)(c2 + 4 * l15);  // clusters 4*l15 .. +3  (== t)
  float c2a[4] = {c2v.x, c2v.y, c2v.z, c2v.w};

  float qv[4][4];
  float rsum[4] = {0.f, 0.f, 0.f, 0.f};
#pragma unroll
  for (int t = 0; t < 4; ++t) {
#pragma unroll
    for (int r = 0; r < 4; ++r) {
      float d2 = fmaxf(x2r[r] + c2a[t] - 2.0f * acc[t][r], 0.f);
      float qq = __builtin_amdgcn_rcpf(1.0f + d2);  // ALPHA=1, exponent 1
      qv[t][r] = qq;
      rsum[r] += qq;
    }
  }
#pragma unroll
  for (int r = 0; r < 4; ++r) {
    rsum[r] += __shfl_xor(rsum[r], 1);
    rsum[r] += __shfl_xor(rsum[r], 2);
    rsum[r] += __shfl_xor(rsum[r], 4);
    rsum[r] += __shfl_xor(rsum[r], 8);
    float inv = __builtin_amdgcn_rcpf(rsum[r]);
    long orow = brow + w * 16 + g * 4 + r;
    float4 o4 = {qv[0][r] * inv, qv[1][r] * inv, qv[2][r] * inv, qv[3][r] * inv};
    *(float4*)(out + orow * 64 + 4 * l15) = o4;  // lane holds clusters 4*l15..+3
  }
#undef STAGE_A
#undef KSTEP
}

extern "C" void kernel_launch(void* const* d_in, const int* in_sizes, int n_in,
                              void* d_out, int out_size, void* d_ws, size_t ws_size,
                              hipStream_t stream) {
  const float* inputs = (const float*)d_in[0];
  const float* clusters = (const float*)d_in[1];
  float* out = (float*)d_out;

  char* cb = (char*)d_ws;                      // 32 KiB pre-swizzled B image
  float* c2 = (float*)((char*)d_ws + 32768);   // 64 floats

  prep_clusters<<<8, 256, 0, stream>>>(clusters, cb, c2);
  cluster_q<<<NPTS / 64, 256, 0, stream>>>(inputs, cb, c2, out);
}